// Round 1
// baseline (696.991 us; speedup 1.0000x reference)
//
#include <hip/hip_runtime.h>
#include <hip/hip_bf16.h>

// Problem constants (from reference setup_inputs)
#define BATCH 8
#define CHAN 128
#define CLASSES 21
#define HW 65536            // 256*256
#define PIX_CHUNKS 4
#define CHUNK (HW / PIX_CHUNKS)   // 16384 pixels per block
#define EPS 1e-8f

// Pass 1: segment sums per (b, class, c) + counts per (b, class).
// Grid: (PIX_CHUNKS, CHAN, BATCH), block 256.
__global__ __launch_bounds__(256) void k_reduce(
    const float* __restrict__ img, const int* __restrict__ gt,
    float* __restrict__ sums, int* __restrict__ counts) {
    __shared__ float ls[CLASSES];
    __shared__ int   lc[CLASSES];
    const int t = threadIdx.x;
    const int chunk = blockIdx.x;
    const int c = blockIdx.y;
    const int b = blockIdx.z;
    if (t < CLASSES) { ls[t] = 0.0f; lc[t] = 0; }
    __syncthreads();

    const float4* __restrict__ imgp =
        (const float4*)(img + ((size_t)(b * CHAN + c)) * HW + (size_t)chunk * CHUNK);
    const int4* __restrict__ gtp =
        (const int4*)(gt + (size_t)b * HW + (size_t)chunk * CHUNK);
    const bool docount = (c == 0);

    #pragma unroll 4
    for (int i = t; i < CHUNK / 4; i += 256) {
        float4 v = imgp[i];
        int4 g = gtp[i];
        unsafeAtomicAdd(&ls[g.x], v.x);
        unsafeAtomicAdd(&ls[g.y], v.y);
        unsafeAtomicAdd(&ls[g.z], v.z);
        unsafeAtomicAdd(&ls[g.w], v.w);
        if (docount) {
            atomicAdd(&lc[g.x], 1);
            atomicAdd(&lc[g.y], 1);
            atomicAdd(&lc[g.z], 1);
            atomicAdd(&lc[g.w], 1);
        }
    }
    __syncthreads();

    if (t < CLASSES) {
        // sums layout: [B][CLASSES][CHAN]
        unsafeAtomicAdd(&sums[((size_t)b * CLASSES + t) * CHAN + c], ls[t]);
        if (docount) atomicAdd(&counts[b * CLASSES + t], lc[t]);
    }
}

// Pass 2: out[b][c][p] = sums[b][gt[p]][c] / (count[b][gt[p]] + EPS)
// Grid: (PIX_CHUNKS, CHAN, BATCH), block 256.
__global__ __launch_bounds__(256) void k_gather(
    const int* __restrict__ gt, const float* __restrict__ sums,
    const int* __restrict__ counts, float* __restrict__ out) {
    __shared__ float m[CLASSES];
    const int t = threadIdx.x;
    const int chunk = blockIdx.x;
    const int c = blockIdx.y;
    const int b = blockIdx.z;
    if (t < CLASSES) {
        float s = sums[((size_t)b * CLASSES + t) * CHAN + c];
        float cnt = (float)counts[b * CLASSES + t];
        m[t] = s / (cnt + EPS);
    }
    __syncthreads();

    const int4* __restrict__ gtp =
        (const int4*)(gt + (size_t)b * HW + (size_t)chunk * CHUNK);
    float4* __restrict__ outp =
        (float4*)(out + ((size_t)(b * CHAN + c)) * HW + (size_t)chunk * CHUNK);

    #pragma unroll 4
    for (int i = t; i < CHUNK / 4; i += 256) {
        int4 g = gtp[i];
        float4 o;
        o.x = m[g.x];
        o.y = m[g.y];
        o.z = m[g.z];
        o.w = m[g.w];
        outp[i] = o;
    }
}

extern "C" void kernel_launch(void* const* d_in, const int* in_sizes, int n_in,
                              void* d_out, int out_size, void* d_ws, size_t ws_size,
                              hipStream_t stream) {
    const float* img = (const float*)d_in[0];
    const int* gt = (const int*)d_in[1];
    float* out = (float*)d_out;

    // Workspace: sums [B*CLASSES*CHAN] f32, counts [B*CLASSES] i32
    float* sums = (float*)d_ws;
    int* counts = (int*)((char*)d_ws + (size_t)BATCH * CLASSES * CHAN * sizeof(float));
    size_t zero_bytes = (size_t)BATCH * CLASSES * CHAN * sizeof(float)
                      + (size_t)BATCH * CLASSES * sizeof(int);
    hipMemsetAsync(d_ws, 0, zero_bytes, stream);

    dim3 grid(PIX_CHUNKS, CHAN, BATCH);
    k_reduce<<<grid, 256, 0, stream>>>(img, gt, sums, counts);
    k_gather<<<grid, 256, 0, stream>>>(gt, sums, counts, out);
}

// Round 2
// 461.867 us; speedup vs baseline: 1.5091x; 1.5091x over previous
//
#include <hip/hip_runtime.h>
#include <hip/hip_bf16.h>

// Problem constants (from reference setup_inputs)
#define BATCH 8
#define CHAN 128
#define CLASSES 21
#define HW 65536            // 256*256
#define PIX_CHUNKS 4
#define CHUNK (HW / PIX_CHUNKS)   // 16384 pixels per block
#define EPS 1e-8f
#define STRIDE 257          // padded row stride: bank(cls*257+t) = (cls+t)%32 -> ~2-way (free)

struct U8x4 { unsigned char x, y, z, w; };

template <typename L>
__device__ __forceinline__ int4 loadLabels4(const L* __restrict__ p, int i);

template <>
__device__ __forceinline__ int4 loadLabels4<int>(const int* __restrict__ p, int i) {
    return ((const int4*)p)[i];
}
template <>
__device__ __forceinline__ int4 loadLabels4<unsigned char>(const unsigned char* __restrict__ p, int i) {
    U8x4 g = ((const U8x4*)p)[i];
    return make_int4(g.x, g.y, g.z, g.w);
}

// Pack gt int32 -> uint8 (4x less label re-read traffic, L2-resident) and count
// per-(b,class) pixel totals. Grid: (HW/1024, BATCH), block 256 (1 int4/thread).
__global__ __launch_bounds__(256) void k_pack_count(
    const int* __restrict__ gt, unsigned char* __restrict__ packed,
    int* __restrict__ counts) {
    __shared__ int lc[CLASSES];
    const int t = threadIdx.x;
    const int b = blockIdx.y;
    const size_t base = (size_t)b * HW + (size_t)blockIdx.x * 1024;
    if (t < CLASSES) lc[t] = 0;
    __syncthreads();
    int4 g = ((const int4*)(gt + base))[t];
    if (packed) {
        U8x4 pk;
        pk.x = (unsigned char)g.x; pk.y = (unsigned char)g.y;
        pk.z = (unsigned char)g.z; pk.w = (unsigned char)g.w;
        ((U8x4*)(packed + base))[t] = pk;
    }
    atomicAdd(&lc[g.x], 1); atomicAdd(&lc[g.y], 1);
    atomicAdd(&lc[g.z], 1); atomicAdd(&lc[g.w], 1);
    __syncthreads();
    if (t < CLASSES) atomicAdd(&counts[b * CLASSES + t], lc[t]);
}

// Pass 1: per-thread privatized accumulators in LDS (NO atomics in the hot loop).
// acc[cls*STRIDE + t]: each thread owns its own column -> plain read-add-write.
// Grid: (PIX_CHUNKS, CHAN, BATCH), block 256.
template <typename L>
__global__ __launch_bounds__(256) void k_reduce(
    const float* __restrict__ img, const L* __restrict__ gt,
    float* __restrict__ sums) {
    __shared__ float acc[CLASSES * STRIDE];
    const int t = threadIdx.x;
    const int chunk = blockIdx.x;
    const int c = blockIdx.y;
    const int b = blockIdx.z;

    #pragma unroll
    for (int cls = 0; cls < CLASSES; ++cls) acc[cls * STRIDE + t] = 0.0f;
    __syncthreads();

    const float4* __restrict__ imgp =
        (const float4*)(img + ((size_t)(b * CHAN + c)) * HW + (size_t)chunk * CHUNK);
    const L* __restrict__ gtp = gt + (size_t)b * HW + (size_t)chunk * CHUNK;
    float* __restrict__ accT = acc + t;   // this thread's column base

    #pragma unroll 4
    for (int i = t; i < CHUNK / 4; i += 256) {
        float4 v = imgp[i];
        int4 g = loadLabels4<L>(gtp, i);
        accT[g.x * STRIDE] += v.x;
        accT[g.y * STRIDE] += v.y;
        accT[g.z * STRIDE] += v.z;
        accT[g.w * STRIDE] += v.w;
    }
    __syncthreads();

    // Tree-reduce the 256 columns. Banks conflict-free-ish (stride 257).
    for (int off = 128; off >= 1; off >>= 1) {
        if (t < off) {
            #pragma unroll
            for (int cls = 0; cls < CLASSES; ++cls)
                acc[cls * STRIDE + t] += acc[cls * STRIDE + t + off];
        }
        __syncthreads();
    }

    if (t < CLASSES)
        unsafeAtomicAdd(&sums[((size_t)b * CLASSES + t) * CHAN + c], acc[t * STRIDE]);
}

// Tiny: means[b][cls][c] = sums / (count + eps). One thread per element.
__global__ __launch_bounds__(256) void k_means(
    const float* __restrict__ sums, const int* __restrict__ counts,
    float* __restrict__ means) {
    int i = blockIdx.x * 256 + threadIdx.x;
    if (i < BATCH * CLASSES * CHAN)
        means[i] = sums[i] / ((float)counts[i / CHAN] + EPS);
}

// Pass 2: out[b][c][p] = means[b][gt[p]][c]. Grid: (PIX_CHUNKS, CHAN, BATCH).
template <typename L>
__global__ __launch_bounds__(256) void k_gather(
    const L* __restrict__ gt, const float* __restrict__ means,
    float* __restrict__ out) {
    __shared__ float m[CLASSES];
    const int t = threadIdx.x;
    const int chunk = blockIdx.x;
    const int c = blockIdx.y;
    const int b = blockIdx.z;
    if (t < CLASSES) m[t] = means[((size_t)b * CLASSES + t) * CHAN + c];
    __syncthreads();

    const L* __restrict__ gtp = gt + (size_t)b * HW + (size_t)chunk * CHUNK;
    float4* __restrict__ outp =
        (float4*)(out + ((size_t)(b * CHAN + c)) * HW + (size_t)chunk * CHUNK);

    #pragma unroll 4
    for (int i = t; i < CHUNK / 4; i += 256) {
        int4 g = loadLabels4<L>(gtp, i);
        float4 o;
        o.x = m[g.x];
        o.y = m[g.y];
        o.z = m[g.z];
        o.w = m[g.w];
        outp[i] = o;
    }
}

extern "C" void kernel_launch(void* const* d_in, const int* in_sizes, int n_in,
                              void* d_out, int out_size, void* d_ws, size_t ws_size,
                              hipStream_t stream) {
    const float* img = (const float*)d_in[0];
    const int* gt = (const int*)d_in[1];
    float* out = (float*)d_out;

    // Workspace layout: sums f32[B*CLS*CHAN] | counts i32[B*CLS] | means f32[B*CLS*CHAN] | packed u8[B*HW]
    size_t off = 0;
    float* sums = (float*)d_ws;
    off += (size_t)BATCH * CLASSES * CHAN * sizeof(float);
    int* counts = (int*)((char*)d_ws + off);
    off += (size_t)BATCH * CLASSES * sizeof(int);
    float* means = (float*)((char*)d_ws + off);
    off += (size_t)BATCH * CLASSES * CHAN * sizeof(float);
    off = (off + 255) & ~(size_t)255;
    unsigned char* packed = (unsigned char*)d_ws + off;
    const bool usePacked = (ws_size >= off + (size_t)BATCH * HW);

    size_t zero_bytes = (size_t)BATCH * CLASSES * CHAN * sizeof(float)
                      + (size_t)BATCH * CLASSES * sizeof(int);
    hipMemsetAsync(d_ws, 0, zero_bytes, stream);

    dim3 gPack(HW / 1024, BATCH);
    k_pack_count<<<gPack, 256, 0, stream>>>(gt, usePacked ? packed : nullptr, counts);

    dim3 grid(PIX_CHUNKS, CHAN, BATCH);
    if (usePacked)
        k_reduce<unsigned char><<<grid, 256, 0, stream>>>(img, packed, sums);
    else
        k_reduce<int><<<grid, 256, 0, stream>>>(img, gt, sums);

    k_means<<<(BATCH * CLASSES * CHAN + 255) / 256, 256, 0, stream>>>(sums, counts, means);

    if (usePacked)
        k_gather<unsigned char><<<grid, 256, 0, stream>>>(packed, means, out);
    else
        k_gather<int><<<grid, 256, 0, stream>>>(gt, means, out);
}